// Round 1
// baseline (180.080 us; speedup 1.0000x reference)
//
#include <hip/hip_runtime.h>

// Problem constants (match reference)
#define NTOK   (64 * 4096)   // B*S tokens
#define DDIM   64            // num_dim
#define NCLUST 256           // num_clusters
#define NFEAT  7             // continuous features (F-1)

// ---------------- kernel 1: per-cluster precompute ----------------
// ws[0..255]   = ||centroid_c||^2
// ws[256..511] = centroid_c . W2
__global__ __launch_bounds__(NCLUST) void precompute_kernel(
    const float* __restrict__ centroids,
    const float* __restrict__ W2,
    float* __restrict__ pre) {
  const int c = threadIdx.x;
  const float4* cp = (const float4*)(centroids + c * DDIM);
  const float4* wp = (const float4*)W2;
  float c2a = 0.f, c2b = 0.f, cwa = 0.f, cwb = 0.f;
#pragma unroll
  for (int i = 0; i < DDIM / 4; i += 2) {
    float4 v0 = cp[i], v1 = cp[i + 1];
    float4 w0 = wp[i], w1 = wp[i + 1];
    c2a = fmaf(v0.x, v0.x, fmaf(v0.y, v0.y, fmaf(v0.z, v0.z, fmaf(v0.w, v0.w, c2a))));
    c2b = fmaf(v1.x, v1.x, fmaf(v1.y, v1.y, fmaf(v1.z, v1.z, fmaf(v1.w, v1.w, c2b))));
    cwa = fmaf(v0.x, w0.x, fmaf(v0.y, w0.y, fmaf(v0.z, w0.z, fmaf(v0.w, w0.w, cwa))));
    cwb = fmaf(v1.x, w1.x, fmaf(v1.y, w1.y, fmaf(v1.z, w1.z, fmaf(v1.w, w1.w, cwb))));
  }
  pre[c] = c2a + c2b;
  pre[NCLUST + c] = cwa + cwb;
}

// ---------------- kernel 2: main fused kernel ----------------
// One thread per token. h[64] in VGPRs. Centroid reads are wave-uniform
// (address depends only on loop counters) -> expect s_load promotion.
__global__ __launch_bounds__(256) void main_kernel(
    const float* __restrict__ x,
    const float* __restrict__ W_embed,
    const float* __restrict__ b_embed,
    const float* __restrict__ emb_table,
    const float* __restrict__ centroids,
    const float* __restrict__ b2,
    const float* __restrict__ pre,
    float* __restrict__ out) {
  const int t = blockIdx.x * 256 + threadIdx.x;
  if (t >= NTOK) return;

  // ---- load token features (8 floats; last is category id) ----
  const float4* xp = (const float4*)(x + (size_t)t * 8);
  const float4 xa = xp[0];
  const float4 xb = xp[1];
  const float xf[NFEAT] = {xa.x, xa.y, xa.z, xa.w, xb.x, xb.y, xb.z};
  const int idx = (int)xb.w;

  // ---- h = emb_table[idx] + b_embed + x[:7] @ W_embed ----
  float h[DDIM];
  {
    const float4* er = (const float4*)(emb_table + (size_t)idx * DDIM);
    const float4* bp = (const float4*)b_embed;
#pragma unroll
    for (int i = 0; i < DDIM / 4; ++i) {
      float4 e = er[i];
      float4 b = bp[i];
      h[4 * i + 0] = e.x + b.x;
      h[4 * i + 1] = e.y + b.y;
      h[4 * i + 2] = e.z + b.z;
      h[4 * i + 3] = e.w + b.w;
    }
  }
#pragma unroll
  for (int f = 0; f < NFEAT; ++f) {
    const float4* wr = (const float4*)(W_embed + f * DDIM);
    const float xv = xf[f];
#pragma unroll
    for (int i = 0; i < DDIM / 4; ++i) {
      float4 w = wr[i];
      h[4 * i + 0] = fmaf(xv, w.x, h[4 * i + 0]);
      h[4 * i + 1] = fmaf(xv, w.y, h[4 * i + 1]);
      h[4 * i + 2] = fmaf(xv, w.z, h[4 * i + 2]);
      h[4 * i + 3] = fmaf(xv, w.w, h[4 * i + 3]);
    }
  }

  // ---- h2 = ||h||^2 (4-way split accumulators) ----
  float p0 = 0.f, p1 = 0.f, p2 = 0.f, p3 = 0.f;
#pragma unroll
  for (int i = 0; i < DDIM / 4; ++i) {
    p0 = fmaf(h[4 * i + 0], h[4 * i + 0], p0);
    p1 = fmaf(h[4 * i + 1], h[4 * i + 1], p1);
    p2 = fmaf(h[4 * i + 2], h[4 * i + 2], p2);
    p3 = fmaf(h[4 * i + 3], h[4 * i + 3], p3);
  }
  const float h2 = (p0 + p1) + (p2 + p3);

  // ---- main loop over clusters ----
  // softmax(-dist) without max-subtraction: dist >= 0 so exp(-dist) <= 1,
  // and dist <= ~40 keeps exp far from fp32 underflow.
  float ssum = 0.f;
  float wsum = 0.f;
  for (int c = 0; c < NCLUST; ++c) {
    const float* cp = centroids + c * DDIM;
    float d0 = 0.f, d1 = 0.f, d2 = 0.f, d3 = 0.f;
#pragma unroll
    for (int i = 0; i < DDIM / 4; ++i) {
      d0 = fmaf(cp[4 * i + 0], h[4 * i + 0], d0);
      d1 = fmaf(cp[4 * i + 1], h[4 * i + 1], d1);
      d2 = fmaf(cp[4 * i + 2], h[4 * i + 2], d2);
      d3 = fmaf(cp[4 * i + 3], h[4 * i + 3], d3);
    }
    const float dot = (d0 + d1) + (d2 + d3);
    const float dd = fmaf(-2.f, dot, h2 + pre[c]);
    const float dist = sqrtf(fmaxf(dd, 0.f));
    const float e = __expf(-dist);
    ssum += e;
    wsum = fmaf(e, pre[NCLUST + c], wsum);
  }

  out[t] = wsum / ssum * 0.125f + b2[0];
}

extern "C" void kernel_launch(void* const* d_in, const int* in_sizes, int n_in,
                              void* d_out, int out_size, void* d_ws, size_t ws_size,
                              hipStream_t stream) {
  const float* x         = (const float*)d_in[0];
  const float* W_embed   = (const float*)d_in[1];
  const float* b_embed   = (const float*)d_in[2];
  const float* emb_table = (const float*)d_in[3];
  const float* centroids = (const float*)d_in[4];
  const float* W2        = (const float*)d_in[5];
  const float* b2        = (const float*)d_in[6];
  float* out = (float*)d_out;
  float* pre = (float*)d_ws;  // 512 floats

  precompute_kernel<<<1, NCLUST, 0, stream>>>(centroids, W2, pre);
  main_kernel<<<NTOK / 256, 256, 0, stream>>>(x, W_embed, b_embed, emb_table,
                                              centroids, b2, pre, out);
}

// Round 2
// 180.000 us; speedup vs baseline: 1.0004x; 1.0004x over previous
//
#include <hip/hip_runtime.h>

// Problem constants (match reference)
#define NTOK   (64 * 4096)   // B*S tokens
#define DDIM   64            // num_dim
#define NCLUST 256           // num_clusters
#define NFEAT  7             // continuous features (F-1)

// ---------------- kernel 1: per-cluster precompute ----------------
// ws[0..255]   = ||centroid_c||^2
// ws[256..511] = centroid_c . W2
__global__ __launch_bounds__(NCLUST) void precompute_kernel(
    const float* __restrict__ centroids,
    const float* __restrict__ W2,
    float* __restrict__ pre) {
  const int c = threadIdx.x;
  const float4* cp = (const float4*)(centroids + c * DDIM);
  const float4* wp = (const float4*)W2;
  float c2a = 0.f, c2b = 0.f, cwa = 0.f, cwb = 0.f;
#pragma unroll
  for (int i = 0; i < DDIM / 4; i += 2) {
    float4 v0 = cp[i], v1 = cp[i + 1];
    float4 w0 = wp[i], w1 = wp[i + 1];
    c2a = fmaf(v0.x, v0.x, fmaf(v0.y, v0.y, fmaf(v0.z, v0.z, fmaf(v0.w, v0.w, c2a))));
    c2b = fmaf(v1.x, v1.x, fmaf(v1.y, v1.y, fmaf(v1.z, v1.z, fmaf(v1.w, v1.w, c2b))));
    cwa = fmaf(v0.x, w0.x, fmaf(v0.y, w0.y, fmaf(v0.z, w0.z, fmaf(v0.w, w0.w, cwa))));
    cwb = fmaf(v1.x, w1.x, fmaf(v1.y, w1.y, fmaf(v1.z, w1.z, fmaf(v1.w, w1.w, cwb))));
  }
  pre[c] = c2a + c2b;
  pre[NCLUST + c] = cwa + cwb;
}

// ---------------- kernel 2: main fused kernel ----------------
// One thread per token, h[64] in VGPRs. __launch_bounds__(256, 4):
// 4 waves/EU == exactly what the 1024-WG grid provides per CU, raising the
// VGPR cap to 128 so h[64] stays in real VGPRs (R1: cap was 48 -> AGPR
// round-trips doubled VALU work). Centroid reads are wave-uniform -> s_load.
__global__ __launch_bounds__(256, 4) void main_kernel(
    const float* __restrict__ x,
    const float* __restrict__ W_embed,
    const float* __restrict__ b_embed,
    const float* __restrict__ emb_table,
    const float* __restrict__ centroids,
    const float* __restrict__ b2,
    const float* __restrict__ pre,
    float* __restrict__ out) {
  const int t = blockIdx.x * 256 + threadIdx.x;
  if (t >= NTOK) return;

  // ---- load token features (8 floats; last is category id) ----
  const float4* xp = (const float4*)(x + (size_t)t * 8);
  const float4 xa = xp[0];
  const float4 xb = xp[1];
  const float xf[NFEAT] = {xa.x, xa.y, xa.z, xa.w, xb.x, xb.y, xb.z};
  const int idx = (int)xb.w;

  // ---- h = emb_table[idx] + b_embed + x[:7] @ W_embed ----
  float h[DDIM];
  {
    const float4* er = (const float4*)(emb_table + (size_t)idx * DDIM);
    const float4* bp = (const float4*)b_embed;
#pragma unroll
    for (int i = 0; i < DDIM / 4; ++i) {
      float4 e = er[i];
      float4 b = bp[i];
      h[4 * i + 0] = e.x + b.x;
      h[4 * i + 1] = e.y + b.y;
      h[4 * i + 2] = e.z + b.z;
      h[4 * i + 3] = e.w + b.w;
    }
  }
#pragma unroll
  for (int f = 0; f < NFEAT; ++f) {
    const float4* wr = (const float4*)(W_embed + f * DDIM);
    const float xv = xf[f];
#pragma unroll
    for (int i = 0; i < DDIM / 4; ++i) {
      float4 w = wr[i];
      h[4 * i + 0] = fmaf(xv, w.x, h[4 * i + 0]);
      h[4 * i + 1] = fmaf(xv, w.y, h[4 * i + 1]);
      h[4 * i + 2] = fmaf(xv, w.z, h[4 * i + 2]);
      h[4 * i + 3] = fmaf(xv, w.w, h[4 * i + 3]);
    }
  }

  // ---- h2 = ||h||^2 (4-way split accumulators) ----
  float p0 = 0.f, p1 = 0.f, p2 = 0.f, p3 = 0.f;
#pragma unroll
  for (int i = 0; i < DDIM / 4; ++i) {
    p0 = fmaf(h[4 * i + 0], h[4 * i + 0], p0);
    p1 = fmaf(h[4 * i + 1], h[4 * i + 1], p1);
    p2 = fmaf(h[4 * i + 2], h[4 * i + 2], p2);
    p3 = fmaf(h[4 * i + 3], h[4 * i + 3], p3);
  }
  const float h2 = (p0 + p1) + (p2 + p3);

  // ---- main loop over clusters ----
  // softmax(-dist) without max-subtraction: dist >= 0 so exp(-dist) <= 1,
  // and dist <= ~40 keeps exp far from fp32 underflow.
  float ssum = 0.f;
  float wsum = 0.f;
  for (int c = 0; c < NCLUST; ++c) {
    const float* cp = centroids + c * DDIM;
    float d0 = 0.f, d1 = 0.f, d2 = 0.f, d3 = 0.f;
#pragma unroll
    for (int i = 0; i < DDIM / 4; ++i) {
      d0 = fmaf(cp[4 * i + 0], h[4 * i + 0], d0);
      d1 = fmaf(cp[4 * i + 1], h[4 * i + 1], d1);
      d2 = fmaf(cp[4 * i + 2], h[4 * i + 2], d2);
      d3 = fmaf(cp[4 * i + 3], h[4 * i + 3], d3);
    }
    const float dot = (d0 + d1) + (d2 + d3);
    const float dd = fmaf(-2.f, dot, h2 + pre[c]);
    const float dist = sqrtf(fmaxf(dd, 0.f));
    const float e = __expf(-dist);
    ssum += e;
    wsum = fmaf(e, pre[NCLUST + c], wsum);
  }

  out[t] = wsum / ssum * 0.125f + b2[0];
}

extern "C" void kernel_launch(void* const* d_in, const int* in_sizes, int n_in,
                              void* d_out, int out_size, void* d_ws, size_t ws_size,
                              hipStream_t stream) {
  const float* x         = (const float*)d_in[0];
  const float* W_embed   = (const float*)d_in[1];
  const float* b_embed   = (const float*)d_in[2];
  const float* emb_table = (const float*)d_in[3];
  const float* centroids = (const float*)d_in[4];
  const float* W2        = (const float*)d_in[5];
  const float* b2        = (const float*)d_in[6];
  float* out = (float*)d_out;
  float* pre = (float*)d_ws;  // 512 floats

  precompute_kernel<<<1, NCLUST, 0, stream>>>(centroids, W2, pre);
  main_kernel<<<NTOK / 256, 256, 0, stream>>>(x, W_embed, b_embed, emb_table,
                                              centroids, b2, pre, out);
}

// Round 3
// 151.542 us; speedup vs baseline: 1.1883x; 1.1878x over previous
//
#include <hip/hip_runtime.h>

// Problem constants
#define NTOK   (64 * 4096)   // B*S tokens
#define DDIM   64            // num_dim
#define NCLUST 256           // num_clusters
#define NFEAT  7             // continuous features

typedef _Float16 f16x8 __attribute__((ext_vector_type(8)));
typedef float    f32x4 __attribute__((ext_vector_type(4)));

// ws layout (floats): [0,256) c2 ; [256,512) cw ; then f16 cent_hi[256*64], cent_lo[256*64]
// total bytes = 2048 + 32768 + 32768 = 67584

// ---- kernel 1a: per-cluster c2 = ||cent||^2, cw = cent . W2 ----
__global__ __launch_bounds__(NCLUST) void precompute_kernel(
    const float* __restrict__ centroids,
    const float* __restrict__ W2,
    float* __restrict__ pre) {
  const int c = threadIdx.x;
  const float4* cp = (const float4*)(centroids + c * DDIM);
  const float4* wp = (const float4*)W2;
  float c2a = 0.f, c2b = 0.f, cwa = 0.f, cwb = 0.f;
#pragma unroll
  for (int i = 0; i < DDIM / 4; i += 2) {
    float4 v0 = cp[i], v1 = cp[i + 1];
    float4 w0 = wp[i], w1 = wp[i + 1];
    c2a = fmaf(v0.x, v0.x, fmaf(v0.y, v0.y, fmaf(v0.z, v0.z, fmaf(v0.w, v0.w, c2a))));
    c2b = fmaf(v1.x, v1.x, fmaf(v1.y, v1.y, fmaf(v1.z, v1.z, fmaf(v1.w, v1.w, c2b))));
    cwa = fmaf(v0.x, w0.x, fmaf(v0.y, w0.y, fmaf(v0.z, w0.z, fmaf(v0.w, w0.w, cwa))));
    cwb = fmaf(v1.x, w1.x, fmaf(v1.y, w1.y, fmaf(v1.z, w1.z, fmaf(v1.w, w1.w, cwb))));
  }
  pre[c] = c2a + c2b;
  pre[NCLUST + c] = cwa + cwb;
}

// ---- kernel 1b: elementwise f16 hi/lo split of centroids ----
__global__ __launch_bounds__(256) void split_kernel(
    const float* __restrict__ centroids,
    _Float16* __restrict__ hi,
    _Float16* __restrict__ lo) {
  const int i = blockIdx.x * 256 + threadIdx.x;  // < 256*64
  const float v = centroids[i];
  const _Float16 h = (_Float16)v;
  hi[i] = h;
  lo[i] = (_Float16)(v - (float)h);
}

// ---- kernel 2: fused main kernel (MFMA) ----
// Block = 256 thr = 4 waves; each wave owns 16 tokens x all 256 clusters.
// No LDS, no __syncthreads: A-fragments of h are computed in-register.
__global__ __launch_bounds__(256, 3) void main_kernel(
    const float* __restrict__ x,
    const float* __restrict__ W_embed,
    const float* __restrict__ b_embed,
    const float* __restrict__ emb_table,
    const float* __restrict__ b2,
    const float* __restrict__ pre,
    const _Float16* __restrict__ cent_hi,
    const _Float16* __restrict__ cent_lo,
    float* __restrict__ out) {
  const int lane = threadIdx.x & 63;
  const int wv   = threadIdx.x >> 6;          // wave in block: 0..3
  const int col  = lane & 15;                 // token row for A / cluster col for B,C
  const int g    = lane >> 4;                 // k-group (0..3)
  const int tokBase = blockIdx.x * 64 + wv * 16;
  const int tok = tokBase + col;

  // ---- token features (4 lanes per token load redundantly; L1-served) ----
  const float4* xp = (const float4*)(x + (size_t)tok * 8);
  const float4 xa = xp[0], xb = xp[1];
  const float xf[NFEAT] = {xa.x, xa.y, xa.z, xa.w, xb.x, xb.y, xb.z};
  const int idx = (int)xb.w;

  // ---- h for this lane's fragment dims: chunk0=[g*8,g*8+8), chunk1=[32+g*8,..) ----
  float h0[8], h1[8];
  {
    const float4* er = (const float4*)(emb_table + (size_t)idx * DDIM);
    const float4* br = (const float4*)b_embed;
    float4 e0 = er[2 * g], e1 = er[2 * g + 1], e2 = er[8 + 2 * g], e3 = er[8 + 2 * g + 1];
    float4 q0 = br[2 * g], q1 = br[2 * g + 1], q2 = br[8 + 2 * g], q3 = br[8 + 2 * g + 1];
    h0[0] = e0.x + q0.x; h0[1] = e0.y + q0.y; h0[2] = e0.z + q0.z; h0[3] = e0.w + q0.w;
    h0[4] = e1.x + q1.x; h0[5] = e1.y + q1.y; h0[6] = e1.z + q1.z; h0[7] = e1.w + q1.w;
    h1[0] = e2.x + q2.x; h1[1] = e2.y + q2.y; h1[2] = e2.z + q2.z; h1[3] = e2.w + q2.w;
    h1[4] = e3.x + q3.x; h1[5] = e3.y + q3.y; h1[6] = e3.z + q3.z; h1[7] = e3.w + q3.w;
  }
#pragma unroll
  for (int f = 0; f < NFEAT; ++f) {
    const float4* wr = (const float4*)(W_embed + f * DDIM);
    const float xv = xf[f];
    float4 w0 = wr[2 * g], w1 = wr[2 * g + 1], w2 = wr[8 + 2 * g], w3 = wr[8 + 2 * g + 1];
    h0[0] = fmaf(xv, w0.x, h0[0]); h0[1] = fmaf(xv, w0.y, h0[1]);
    h0[2] = fmaf(xv, w0.z, h0[2]); h0[3] = fmaf(xv, w0.w, h0[3]);
    h0[4] = fmaf(xv, w1.x, h0[4]); h0[5] = fmaf(xv, w1.y, h0[5]);
    h0[6] = fmaf(xv, w1.z, h0[6]); h0[7] = fmaf(xv, w1.w, h0[7]);
    h1[0] = fmaf(xv, w2.x, h1[0]); h1[1] = fmaf(xv, w2.y, h1[1]);
    h1[2] = fmaf(xv, w2.z, h1[2]); h1[3] = fmaf(xv, w2.w, h1[3]);
    h1[4] = fmaf(xv, w3.x, h1[4]); h1[5] = fmaf(xv, w3.y, h1[5]);
    h1[6] = fmaf(xv, w3.z, h1[6]); h1[7] = fmaf(xv, w3.w, h1[7]);
  }

  // ---- h2 = ||h||^2 per token (partial over this lane's 16 dims, then xor 16,32) ----
  float ptl = 0.f;
#pragma unroll
  for (int i = 0; i < 8; ++i) {
    ptl = fmaf(h0[i], h0[i], ptl);
    ptl = fmaf(h1[i], h1[i], ptl);
  }
  ptl += __shfl_xor(ptl, 16);
  ptl += __shfl_xor(ptl, 32);   // now ptl = h2 of token (lane&15), on every lane
  // redistribute to C-layout rows: row r holds token g*4+r
  float hb[4];
#pragma unroll
  for (int r = 0; r < 4; ++r) hb[r] = __shfl(ptl, g * 4 + r);

  // ---- f16 hi/lo split of A fragments ----
  f16x8 ah0, al0, ah1, al1;
#pragma unroll
  for (int i = 0; i < 8; ++i) {
    _Float16 hi0 = (_Float16)h0[i];
    ah0[i] = hi0; al0[i] = (_Float16)(h0[i] - (float)hi0);
    _Float16 hi1 = (_Float16)h1[i];
    ah1[i] = hi1; al1[i] = (_Float16)(h1[i] - (float)hi1);
  }

  // ---- main loop: 16 cluster tiles of 16 ----
  const float* c2g = pre;
  const float* cwg = pre + NCLUST;
  float ss[4] = {0.f, 0.f, 0.f, 0.f};
  float ww[4] = {0.f, 0.f, 0.f, 0.f};
#pragma unroll 2
  for (int t = 0; t < 16; ++t) {
    const int c = t * 16 + col;
    const _Float16* cb = cent_hi + c * DDIM + g * 8;
    const _Float16* cl = cent_lo + c * DDIM + g * 8;
    f16x8 bh0 = *(const f16x8*)(cb);
    f16x8 bh1 = *(const f16x8*)(cb + 32);
    f16x8 bl0 = *(const f16x8*)(cl);
    f16x8 bl1 = *(const f16x8*)(cl + 32);
    f32x4 hh = {0.f, 0.f, 0.f, 0.f};
    f32x4 hl = {0.f, 0.f, 0.f, 0.f};
    f32x4 lh = {0.f, 0.f, 0.f, 0.f};
    hh = __builtin_amdgcn_mfma_f32_16x16x32_f16(ah0, bh0, hh, 0, 0, 0);
    hl = __builtin_amdgcn_mfma_f32_16x16x32_f16(ah0, bl0, hl, 0, 0, 0);
    lh = __builtin_amdgcn_mfma_f32_16x16x32_f16(al0, bh0, lh, 0, 0, 0);
    hh = __builtin_amdgcn_mfma_f32_16x16x32_f16(ah1, bh1, hh, 0, 0, 0);
    hl = __builtin_amdgcn_mfma_f32_16x16x32_f16(ah1, bl1, hl, 0, 0, 0);
    lh = __builtin_amdgcn_mfma_f32_16x16x32_f16(al1, bh1, lh, 0, 0, 0);
    const float c2c = c2g[c];
    const float cwc = cwg[c];
#pragma unroll
    for (int r = 0; r < 4; ++r) {
      const float dot = hh[r] + (hl[r] + lh[r]);
      const float d2 = fmaf(-2.f, dot, hb[r] + c2c);
      const float e = __expf(-sqrtf(fmaxf(d2, 0.f)));
      ss[r] += e;
      ww[r] = fmaf(e, cwc, ww[r]);
    }
  }

  // ---- reduce over the 16 cluster-lanes, store 16 tokens per wave ----
  const float b2v = b2[0];
#pragma unroll
  for (int r = 0; r < 4; ++r) {
    float s = ss[r], w = ww[r];
    s += __shfl_xor(s, 1); w += __shfl_xor(w, 1);
    s += __shfl_xor(s, 2); w += __shfl_xor(w, 2);
    s += __shfl_xor(s, 4); w += __shfl_xor(w, 4);
    s += __shfl_xor(s, 8); w += __shfl_xor(w, 8);
    if (col == 0) out[tokBase + g * 4 + r] = w / s * 0.125f + b2v;
  }
}

extern "C" void kernel_launch(void* const* d_in, const int* in_sizes, int n_in,
                              void* d_out, int out_size, void* d_ws, size_t ws_size,
                              hipStream_t stream) {
  const float* x         = (const float*)d_in[0];
  const float* W_embed   = (const float*)d_in[1];
  const float* b_embed   = (const float*)d_in[2];
  const float* emb_table = (const float*)d_in[3];
  const float* centroids = (const float*)d_in[4];
  const float* W2        = (const float*)d_in[5];
  const float* b2        = (const float*)d_in[6];
  float* out = (float*)d_out;

  float* pre = (float*)d_ws;                            // 512 floats
  _Float16* cent_hi = (_Float16*)((char*)d_ws + 2048);  // 256*64 f16
  _Float16* cent_lo = cent_hi + NCLUST * DDIM;          // 256*64 f16

  precompute_kernel<<<1, NCLUST, 0, stream>>>(centroids, W2, pre);
  split_kernel<<<(NCLUST * DDIM) / 256, 256, 0, stream>>>(centroids, cent_hi, cent_lo);
  main_kernel<<<NTOK / 64, 256, 0, stream>>>(x, W_embed, b_embed, emb_table,
                                             b2, pre, cent_hi, cent_lo, out);
}

// Round 5
// 91.380 us; speedup vs baseline: 1.9707x; 1.6584x over previous
//
#include <hip/hip_runtime.h>

// Problem constants
#define NTOK   (64 * 4096)   // B*S tokens
#define DDIM   64            // num_dim
#define NCLUST 256           // num_clusters
#define NFEAT  7             // continuous features

typedef _Float16 f16x8 __attribute__((ext_vector_type(8)));
typedef float    f32x4 __attribute__((ext_vector_type(4)));

// ws layout: [0, 2048) float pre[512] = c2[256] ++ cw[256]
//            [2048, 2048+65536) _Float16 cent_swz[256*128]
// cent_swz row c: 16 chunks of 8 halves (16B). Chunk j holds:
//   j in [0,8):  f16-hi of cent[c][j*8 .. j*8+8)
//   j in [8,16): f16-lo of cent[c][(j-8)*8 .. +8)
// stored at position (j ^ (c&7))  [XOR swizzle, bank-conflict-free ds_read_b128]

// ---- kernel 1a: per-cluster c2 / cw (R3-verified, verbatim) ----
__global__ __launch_bounds__(NCLUST) void precompute_kernel(
    const float* __restrict__ centroids,
    const float* __restrict__ W2,
    float* __restrict__ pre) {
  const int c = threadIdx.x;
  const float4* cp = (const float4*)(centroids + c * DDIM);
  const float4* wp = (const float4*)W2;
  float c2a = 0.f, c2b = 0.f, cwa = 0.f, cwb = 0.f;
#pragma unroll
  for (int i = 0; i < DDIM / 4; i += 2) {
    float4 v0 = cp[i], v1 = cp[i + 1];
    float4 w0 = wp[i], w1 = wp[i + 1];
    c2a = fmaf(v0.x, v0.x, fmaf(v0.y, v0.y, fmaf(v0.z, v0.z, fmaf(v0.w, v0.w, c2a))));
    c2b = fmaf(v1.x, v1.x, fmaf(v1.y, v1.y, fmaf(v1.z, v1.z, fmaf(v1.w, v1.w, c2b))));
    cwa = fmaf(v0.x, w0.x, fmaf(v0.y, w0.y, fmaf(v0.z, w0.z, fmaf(v0.w, w0.w, cwa))));
    cwb = fmaf(v1.x, w1.x, fmaf(v1.y, w1.y, fmaf(v1.z, w1.z, fmaf(v1.w, w1.w, cwb))));
  }
  pre[c] = c2a + c2b;
  pre[NCLUST + c] = cwa + cwb;
}

// ---- kernel 1b: f16 hi/lo split -> XOR-swizzled chunk layout ----
__global__ __launch_bounds__(256) void split_kernel(
    const float* __restrict__ centroids,
    _Float16* __restrict__ cent_swz) {
  const int tid = blockIdx.x * 256 + threadIdx.x;  // 0..4095
  const int c = tid >> 4;
  const int j = tid & 15;
  const int d0 = (j & 7) * 8;
  const bool lo = (j >= 8);
  f16x8 v;
#pragma unroll
  for (int i = 0; i < 8; ++i) {
    const float f = centroids[c * DDIM + d0 + i];
    const _Float16 h = (_Float16)f;
    v[i] = lo ? (_Float16)(f - (float)h) : h;
  }
  *(f16x8*)&cent_swz[c * 128 + (j ^ (c & 7)) * 8] = v;
}

// ---- kernel 2: fused main kernel (R3 math verbatim; B from LDS) ----
// 4 waves/block; wave = 16 tokens x 256 clusters. Block stages all centroid
// hi/lo fragments (64KB) into LDS once; ds_read_b128 with the same XOR swizzle.
__global__ __launch_bounds__(256) void main_kernel(
    const float* __restrict__ x,
    const float* __restrict__ W_embed,
    const float* __restrict__ b_embed,
    const float* __restrict__ emb_table,
    const float* __restrict__ b2,
    const float* __restrict__ pre,
    const _Float16* __restrict__ cent_swz,
    float* __restrict__ out) {
  extern __shared__ _Float16 s_cent[];   // 256*128 halves = 65536 B

  const int tid  = threadIdx.x;
  const int lane = tid & 63;
  const int wv   = tid >> 6;          // wave in block: 0..3
  const int col  = lane & 15;         // A-row (token) / B,C-col (cluster)
  const int g    = lane >> 4;         // k-group (0..3)
  const int tokBase = blockIdx.x * 64 + wv * 16;
  const int tok = tokBase + col;

  // ---- stage cent_swz -> LDS (linear 64KB copy; swizzle preserved) ----
  {
    const float4* gsrc = (const float4*)cent_swz;   // 4096 float4
    float4* ldst = (float4*)s_cent;
#pragma unroll
    for (int i = 0; i < 16; ++i)
      ldst[tid + 256 * i] = gsrc[tid + 256 * i];
  }

  // ---- prologue: token features ----
  const float4* xp = (const float4*)(x + (size_t)tok * 8);
  const float4 xa = xp[0], xb = xp[1];
  const float xf[NFEAT] = {xa.x, xa.y, xa.z, xa.w, xb.x, xb.y, xb.z};
  const int idx = (int)xb.w;

  // ---- h for this lane's fragment dims: [g*8..+8) and [32+g*8..+8) ----
  float h0[8], h1[8];
  {
    const float4* er = (const float4*)(emb_table + (size_t)idx * DDIM);
    const float4* br = (const float4*)b_embed;
    float4 e0 = er[2 * g], e1 = er[2 * g + 1], e2 = er[8 + 2 * g], e3 = er[8 + 2 * g + 1];
    float4 q0 = br[2 * g], q1 = br[2 * g + 1], q2 = br[8 + 2 * g], q3 = br[8 + 2 * g + 1];
    h0[0] = e0.x + q0.x; h0[1] = e0.y + q0.y; h0[2] = e0.z + q0.z; h0[3] = e0.w + q0.w;
    h0[4] = e1.x + q1.x; h0[5] = e1.y + q1.y; h0[6] = e1.z + q1.z; h0[7] = e1.w + q1.w;
    h1[0] = e2.x + q2.x; h1[1] = e2.y + q2.y; h1[2] = e2.z + q2.z; h1[3] = e2.w + q2.w;
    h1[4] = e3.x + q3.x; h1[5] = e3.y + q3.y; h1[6] = e3.z + q3.z; h1[7] = e3.w + q3.w;
  }
#pragma unroll
  for (int f = 0; f < NFEAT; ++f) {
    const float4* wr = (const float4*)(W_embed + f * DDIM);
    const float xv = xf[f];
    float4 w0 = wr[2 * g], w1 = wr[2 * g + 1], w2 = wr[8 + 2 * g], w3 = wr[8 + 2 * g + 1];
    h0[0] = fmaf(xv, w0.x, h0[0]); h0[1] = fmaf(xv, w0.y, h0[1]);
    h0[2] = fmaf(xv, w0.z, h0[2]); h0[3] = fmaf(xv, w0.w, h0[3]);
    h0[4] = fmaf(xv, w1.x, h0[4]); h0[5] = fmaf(xv, w1.y, h0[5]);
    h0[6] = fmaf(xv, w1.z, h0[6]); h0[7] = fmaf(xv, w1.w, h0[7]);
    h1[0] = fmaf(xv, w2.x, h1[0]); h1[1] = fmaf(xv, w2.y, h1[1]);
    h1[2] = fmaf(xv, w2.z, h1[2]); h1[3] = fmaf(xv, w2.w, h1[3]);
    h1[4] = fmaf(xv, w3.x, h1[4]); h1[5] = fmaf(xv, w3.y, h1[5]);
    h1[6] = fmaf(xv, w3.z, h1[6]); h1[7] = fmaf(xv, w3.w, h1[7]);
  }

  // ---- h2 partial -> full h2 of token (lane&15) -> C rows ----
  float ptl = 0.f;
#pragma unroll
  for (int i = 0; i < 8; ++i) {
    ptl = fmaf(h0[i], h0[i], ptl);
    ptl = fmaf(h1[i], h1[i], ptl);
  }
  ptl += __shfl_xor(ptl, 16);
  ptl += __shfl_xor(ptl, 32);
  float hb[4];
#pragma unroll
  for (int r = 0; r < 4; ++r) hb[r] = __shfl(ptl, g * 4 + r);

  // ---- f16 hi/lo split of A fragments ----
  f16x8 ah0, al0, ah1, al1;
#pragma unroll
  for (int i = 0; i < 8; ++i) {
    _Float16 t0 = (_Float16)h0[i];
    ah0[i] = t0; al0[i] = (_Float16)(h0[i] - (float)t0);
    _Float16 t1 = (_Float16)h1[i];
    ah1[i] = t1; al1[i] = (_Float16)(h1[i] - (float)t1);
  }

  __syncthreads();   // LDS stage complete

  // ---- main loop: 16 cluster tiles of 16, B-fragments from LDS ----
  const float* c2g = pre;
  const float* cwg = pre + NCLUST;
  float ss[4] = {0.f, 0.f, 0.f, 0.f};
  float ww[4] = {0.f, 0.f, 0.f, 0.f};
#pragma unroll 2
  for (int t = 0; t < 16; ++t) {
    const int c = t * 16 + col;
    const int sw = c & 7;
    const _Float16* row = s_cent + c * 128;
    const f16x8 bh0 = *(const f16x8*)(row + ((g    ) ^ sw) * 8);
    const f16x8 bh1 = *(const f16x8*)(row + ((4 + g) ^ sw) * 8);
    const f16x8 bl0 = *(const f16x8*)(row + ((8 + g) ^ sw) * 8);
    const f16x8 bl1 = *(const f16x8*)(row + ((12 + g) ^ sw) * 8);
    f32x4 hh = {0.f, 0.f, 0.f, 0.f};
    f32x4 hl = {0.f, 0.f, 0.f, 0.f};
    f32x4 lh = {0.f, 0.f, 0.f, 0.f};
    hh = __builtin_amdgcn_mfma_f32_16x16x32_f16(ah0, bh0, hh, 0, 0, 0);
    hl = __builtin_amdgcn_mfma_f32_16x16x32_f16(ah0, bl0, hl, 0, 0, 0);
    lh = __builtin_amdgcn_mfma_f32_16x16x32_f16(al0, bh0, lh, 0, 0, 0);
    hh = __builtin_amdgcn_mfma_f32_16x16x32_f16(ah1, bh1, hh, 0, 0, 0);
    hl = __builtin_amdgcn_mfma_f32_16x16x32_f16(ah1, bl1, hl, 0, 0, 0);
    lh = __builtin_amdgcn_mfma_f32_16x16x32_f16(al1, bh1, lh, 0, 0, 0);
    const float c2c = c2g[c];
    const float cwc = cwg[c];
#pragma unroll
    for (int r = 0; r < 4; ++r) {
      const float dot = hh[r] + (hl[r] + lh[r]);
      const float d2 = fmaf(-2.f, dot, hb[r] + c2c);
      const float e = __expf(-sqrtf(fmaxf(d2, 0.f)));
      ss[r] += e;
      ww[r] = fmaf(e, cwc, ww[r]);
    }
  }

  // ---- reduce over the 16 cluster-lanes, store 16 tokens per wave ----
  const float b2v = b2[0];
#pragma unroll
  for (int r = 0; r < 4; ++r) {
    float s = ss[r], w = ww[r];
    s += __shfl_xor(s, 1); w += __shfl_xor(w, 1);
    s += __shfl_xor(s, 2); w += __shfl_xor(w, 2);
    s += __shfl_xor(s, 4); w += __shfl_xor(w, 4);
    s += __shfl_xor(s, 8); w += __shfl_xor(w, 8);
    if (col == 0) out[tokBase + g * 4 + r] = w / s * 0.125f + b2v;
  }
}

extern "C" void kernel_launch(void* const* d_in, const int* in_sizes, int n_in,
                              void* d_out, int out_size, void* d_ws, size_t ws_size,
                              hipStream_t stream) {
  const float* x         = (const float*)d_in[0];
  const float* W_embed   = (const float*)d_in[1];
  const float* b_embed   = (const float*)d_in[2];
  const float* emb_table = (const float*)d_in[3];
  const float* centroids = (const float*)d_in[4];
  const float* W2        = (const float*)d_in[5];
  const float* b2        = (const float*)d_in[6];
  float* out = (float*)d_out;

  float* pre = (float*)d_ws;                              // 512 floats
  _Float16* cent_swz = (_Float16*)((char*)d_ws + 2048);   // 256*128 f16

  precompute_kernel<<<1, NCLUST, 0, stream>>>(centroids, W2, pre);
  split_kernel<<<(NCLUST * 16) / 256, 256, 0, stream>>>(centroids, cent_swz);
  main_kernel<<<NTOK / 64, 256, 65536, stream>>>(x, W_embed, b_embed, emb_table,
                                                 b2, pre, cent_swz, out);
}

// Round 6
// 82.175 us; speedup vs baseline: 2.1914x; 1.1120x over previous
//
#include <hip/hip_runtime.h>

// Problem constants
#define NTOK   (64 * 4096)   // B*S tokens
#define DDIM   64            // num_dim
#define NCLUST 256           // num_clusters
#define NFEAT  7             // continuous features
#define RT     4             // row-tiles of 16 tokens per wave

typedef _Float16 f16x8 __attribute__((ext_vector_type(8)));
typedef float    f32x4 __attribute__((ext_vector_type(4)));

// ws layout: [0, 2048) float pre[512] = c2[256] ++ cw[256]
//            [2048, 2048+65536) _Float16 cent_swz[256*128]
// cent_swz row c: 16 chunks of 8 halves (16B):
//   chunk j in [0,8):  f16-hi of cent[c][j*8 .. j*8+8)
//   chunk j in [8,16): f16-lo of cent[c][(j-8)*8 .. +8)
// stored at chunk position (j ^ (c&7))  [XOR swizzle for ds_read_b128]

// ---- kernel 1a: per-cluster c2 / cw (verified R3/R5, verbatim) ----
__global__ __launch_bounds__(NCLUST) void precompute_kernel(
    const float* __restrict__ centroids,
    const float* __restrict__ W2,
    float* __restrict__ pre) {
  const int c = threadIdx.x;
  const float4* cp = (const float4*)(centroids + c * DDIM);
  const float4* wp = (const float4*)W2;
  float c2a = 0.f, c2b = 0.f, cwa = 0.f, cwb = 0.f;
#pragma unroll
  for (int i = 0; i < DDIM / 4; i += 2) {
    float4 v0 = cp[i], v1 = cp[i + 1];
    float4 w0 = wp[i], w1 = wp[i + 1];
    c2a = fmaf(v0.x, v0.x, fmaf(v0.y, v0.y, fmaf(v0.z, v0.z, fmaf(v0.w, v0.w, c2a))));
    c2b = fmaf(v1.x, v1.x, fmaf(v1.y, v1.y, fmaf(v1.z, v1.z, fmaf(v1.w, v1.w, c2b))));
    cwa = fmaf(v0.x, w0.x, fmaf(v0.y, w0.y, fmaf(v0.z, w0.z, fmaf(v0.w, w0.w, cwa))));
    cwb = fmaf(v1.x, w1.x, fmaf(v1.y, w1.y, fmaf(v1.z, w1.z, fmaf(v1.w, w1.w, cwb))));
  }
  pre[c] = c2a + c2b;
  pre[NCLUST + c] = cwa + cwb;
}

// ---- kernel 1b: f16 hi/lo split -> XOR-swizzled chunk layout (verified R5) ----
__global__ __launch_bounds__(256) void split_kernel(
    const float* __restrict__ centroids,
    _Float16* __restrict__ cent_swz) {
  const int tid = blockIdx.x * 256 + threadIdx.x;  // 0..4095
  const int c = tid >> 4;
  const int j = tid & 15;
  const int d0 = (j & 7) * 8;
  const bool lo = (j >= 8);
  f16x8 v;
#pragma unroll
  for (int i = 0; i < 8; ++i) {
    const float f = centroids[c * DDIM + d0 + i];
    const _Float16 h = (_Float16)f;
    v[i] = lo ? (_Float16)(f - (float)h) : h;
  }
  *(f16x8*)&cent_swz[c * 128 + (j ^ (c & 7)) * 8] = v;
}

// ---- kernel 2: fused main kernel (R5 math; RT=4 row-tiles per wave) ----
// 4 waves/block, wave = 64 tokens x 256 clusters. B-fragments + c2/cw loaded
// once per cluster-tile, reused by 4 row-tiles. All fragments individually
// named (no runtime-indexable ext_vector arrays).
__global__ __launch_bounds__(256, 2) void main_kernel(
    const float* __restrict__ x,
    const float* __restrict__ W_embed,
    const float* __restrict__ b_embed,
    const float* __restrict__ emb_table,
    const float* __restrict__ b2,
    const float* __restrict__ pre,
    const _Float16* __restrict__ cent_swz,
    float* __restrict__ out) {
  extern __shared__ _Float16 s_cent[];   // 256*128 halves = 65536 B

  const int tid  = threadIdx.x;
  const int lane = tid & 63;
  const int wv   = tid >> 6;          // wave in block: 0..3
  const int col  = lane & 15;         // A-row (token) / B,C-col (cluster)
  const int g    = lane >> 4;         // k-group (0..3)
  const int tokBase = blockIdx.x * (64 * RT) + wv * (16 * RT);

  // ---- stage cent_swz -> LDS (linear 64KB copy; swizzle preserved) ----
  {
    const float4* gsrc = (const float4*)cent_swz;   // 4096 float4
    float4* ldst = (float4*)s_cent;
#pragma unroll
    for (int i = 0; i < 16; ++i)
      ldst[tid + 256 * i] = gsrc[tid + 256 * i];
  }

  // ---- b_embed fragment (token-independent) ----
  const float4* br = (const float4*)b_embed;
  const float4 q0 = br[2 * g], q1 = br[2 * g + 1];
  const float4 q2 = br[8 + 2 * g], q3 = br[8 + 2 * g + 1];

  // ---- prologue: h[rt][0..7]=dims[g*8..+8), h[rt][8..15]=dims[32+g*8..+8) ----
  float h[RT][16];
  float xf[RT][NFEAT];
#pragma unroll
  for (int rt = 0; rt < RT; ++rt) {
    const int tok = tokBase + rt * 16 + col;
    const float4* xp = (const float4*)(x + (size_t)tok * 8);
    const float4 xa = xp[0], xb = xp[1];
    xf[rt][0] = xa.x; xf[rt][1] = xa.y; xf[rt][2] = xa.z; xf[rt][3] = xa.w;
    xf[rt][4] = xb.x; xf[rt][5] = xb.y; xf[rt][6] = xb.z;
    const int idx = (int)xb.w;
    const float4* er = (const float4*)(emb_table + (size_t)idx * DDIM);
    const float4 e0 = er[2 * g], e1 = er[2 * g + 1];
    const float4 e2 = er[8 + 2 * g], e3 = er[8 + 2 * g + 1];
    h[rt][0]  = e0.x + q0.x; h[rt][1]  = e0.y + q0.y;
    h[rt][2]  = e0.z + q0.z; h[rt][3]  = e0.w + q0.w;
    h[rt][4]  = e1.x + q1.x; h[rt][5]  = e1.y + q1.y;
    h[rt][6]  = e1.z + q1.z; h[rt][7]  = e1.w + q1.w;
    h[rt][8]  = e2.x + q2.x; h[rt][9]  = e2.y + q2.y;
    h[rt][10] = e2.z + q2.z; h[rt][11] = e2.w + q2.w;
    h[rt][12] = e3.x + q3.x; h[rt][13] = e3.y + q3.y;
    h[rt][14] = e3.z + q3.z; h[rt][15] = e3.w + q3.w;
  }
  // W_embed: f outer (W fragment loaded once), rt inner (reused 4x)
#pragma unroll
  for (int f = 0; f < NFEAT; ++f) {
    const float4* wr = (const float4*)(W_embed + f * DDIM);
    const float4 w0 = wr[2 * g], w1 = wr[2 * g + 1];
    const float4 w2 = wr[8 + 2 * g], w3 = wr[8 + 2 * g + 1];
#pragma unroll
    for (int rt = 0; rt < RT; ++rt) {
      const float xv = xf[rt][f];
      h[rt][0]  = fmaf(xv, w0.x, h[rt][0]);  h[rt][1]  = fmaf(xv, w0.y, h[rt][1]);
      h[rt][2]  = fmaf(xv, w0.z, h[rt][2]);  h[rt][3]  = fmaf(xv, w0.w, h[rt][3]);
      h[rt][4]  = fmaf(xv, w1.x, h[rt][4]);  h[rt][5]  = fmaf(xv, w1.y, h[rt][5]);
      h[rt][6]  = fmaf(xv, w1.z, h[rt][6]);  h[rt][7]  = fmaf(xv, w1.w, h[rt][7]);
      h[rt][8]  = fmaf(xv, w2.x, h[rt][8]);  h[rt][9]  = fmaf(xv, w2.y, h[rt][9]);
      h[rt][10] = fmaf(xv, w2.z, h[rt][10]); h[rt][11] = fmaf(xv, w2.w, h[rt][11]);
      h[rt][12] = fmaf(xv, w3.x, h[rt][12]); h[rt][13] = fmaf(xv, w3.y, h[rt][13]);
      h[rt][14] = fmaf(xv, w3.z, h[rt][14]); h[rt][15] = fmaf(xv, w3.w, h[rt][15]);
    }
  }

  // ---- per-rt: h2 reduce + f16 hi/lo split into NAMED fragments ----
  f16x8 ah0_0, al0_0, ah1_0, al1_0; float hb_0[4];
  f16x8 ah0_1, al0_1, ah1_1, al1_1; float hb_1[4];
  f16x8 ah0_2, al0_2, ah1_2, al1_2; float hb_2[4];
  f16x8 ah0_3, al0_3, ah1_3, al1_3; float hb_3[4];

#define SPLIT_RT(RTI, AH0, AL0, AH1, AL1, HB) do {                          \
    float ptl = 0.f;                                                        \
    _Pragma("unroll") for (int i = 0; i < 8; ++i) {                         \
      ptl = fmaf(h[RTI][i], h[RTI][i], ptl);                                \
      ptl = fmaf(h[RTI][8 + i], h[RTI][8 + i], ptl);                        \
    }                                                                       \
    ptl += __shfl_xor(ptl, 16);                                             \
    ptl += __shfl_xor(ptl, 32);                                             \
    _Pragma("unroll") for (int r = 0; r < 4; ++r)                           \
      HB[r] = __shfl(ptl, g * 4 + r);                                       \
    _Pragma("unroll") for (int i = 0; i < 8; ++i) {                         \
      _Float16 t0 = (_Float16)h[RTI][i];                                    \
      AH0[i] = t0; AL0[i] = (_Float16)(h[RTI][i] - (float)t0);              \
      _Float16 t1 = (_Float16)h[RTI][8 + i];                                \
      AH1[i] = t1; AL1[i] = (_Float16)(h[RTI][8 + i] - (float)t1);          \
    }                                                                       \
  } while (0)

  SPLIT_RT(0, ah0_0, al0_0, ah1_0, al1_0, hb_0);
  SPLIT_RT(1, ah0_1, al0_1, ah1_1, al1_1, hb_1);
  SPLIT_RT(2, ah0_2, al0_2, ah1_2, al1_2, hb_2);
  SPLIT_RT(3, ah0_3, al0_3, ah1_3, al1_3, hb_3);
#undef SPLIT_RT

  __syncthreads();   // LDS stage complete

  // ---- main loop: 16 cluster tiles; B + c2/cw shared across 4 row-tiles ----
  const float* c2g = pre;
  const float* cwg = pre + NCLUST;
  float ss_0[4] = {0.f, 0.f, 0.f, 0.f}, ww_0[4] = {0.f, 0.f, 0.f, 0.f};
  float ss_1[4] = {0.f, 0.f, 0.f, 0.f}, ww_1[4] = {0.f, 0.f, 0.f, 0.f};
  float ss_2[4] = {0.f, 0.f, 0.f, 0.f}, ww_2[4] = {0.f, 0.f, 0.f, 0.f};
  float ss_3[4] = {0.f, 0.f, 0.f, 0.f}, ww_3[4] = {0.f, 0.f, 0.f, 0.f};

#pragma unroll 2
  for (int t = 0; t < 16; ++t) {
    const int c = t * 16 + col;
    const int sw = c & 7;
    const _Float16* row = s_cent + c * 128;
    const f16x8 bh0 = *(const f16x8*)(row + ((g     ) ^ sw) * 8);
    const f16x8 bh1 = *(const f16x8*)(row + ((4 + g ) ^ sw) * 8);
    const f16x8 bl0 = *(const f16x8*)(row + ((8 + g ) ^ sw) * 8);
    const f16x8 bl1 = *(const f16x8*)(row + ((12 + g) ^ sw) * 8);
    const float c2c = c2g[c];
    const float cwc = cwg[c];

#define DO_RT(AH0, AL0, AH1, AL1, HB, SS, WW) do {                          \
    f32x4 hh = {0.f, 0.f, 0.f, 0.f};                                       \
    f32x4 hl = {0.f, 0.f, 0.f, 0.f};                                       \
    f32x4 lh = {0.f, 0.f, 0.f, 0.f};                                       \
    hh = __builtin_amdgcn_mfma_f32_16x16x32_f16(AH0, bh0, hh, 0, 0, 0);     \
    hl = __builtin_amdgcn_mfma_f32_16x16x32_f16(AH0, bl0, hl, 0, 0, 0);     \
    lh = __builtin_amdgcn_mfma_f32_16x16x32_f16(AL0, bh0, lh, 0, 0, 0);     \
    hh = __builtin_amdgcn_mfma_f32_16x16x32_f16(AH1, bh1, hh, 0, 0, 0);     \
    hl = __builtin_amdgcn_mfma_f32_16x16x32_f16(AH1, bl1, hl, 0, 0, 0);     \
    lh = __builtin_amdgcn_mfma_f32_16x16x32_f16(AL1, bh1, lh, 0, 0, 0);     \
    _Pragma("unroll") for (int r = 0; r < 4; ++r) {                         \
      const float dot = hh[r] + (hl[r] + lh[r]);                            \
      const float d2 = fmaf(-2.f, dot, HB[r] + c2c);                        \
      const float e = __expf(-sqrtf(fmaxf(d2, 0.f)));                       \
      SS[r] += e;                                                           \
      WW[r] = fmaf(e, cwc, WW[r]);                                         \
    }                                                                       \
  } while (0)

    DO_RT(ah0_0, al0_0, ah1_0, al1_0, hb_0, ss_0, ww_0);
    DO_RT(ah0_1, al0_1, ah1_1, al1_1, hb_1, ss_1, ww_1);
    DO_RT(ah0_2, al0_2, ah1_2, al1_2, hb_2, ss_2, ww_2);
    DO_RT(ah0_3, al0_3, ah1_3, al1_3, hb_3, ss_3, ww_3);
#undef DO_RT
  }

  // ---- reduce over the 16 cluster-lanes, store 64 tokens per wave ----
  const float b2v = b2[0];
#define STORE_RT(RTI, SS, WW) do {                                          \
    _Pragma("unroll") for (int r = 0; r < 4; ++r) {                         \
      float s = SS[r], w = WW[r];                                           \
      s += __shfl_xor(s, 1); w += __shfl_xor(w, 1);                         \
      s += __shfl_xor(s, 2); w += __shfl_xor(w, 2);                         \
      s += __shfl_xor(s, 4); w += __shfl_xor(w, 4);                         \
      s += __shfl_xor(s, 8); w += __shfl_xor(w, 8);                         \
      if (col == 0)                                                         \
        out[tokBase + (RTI) * 16 + g * 4 + r] = w / s * 0.125f + b2v;       \
    }                                                                       \
  } while (0)

  STORE_RT(0, ss_0, ww_0);
  STORE_RT(1, ss_1, ww_1);
  STORE_RT(2, ss_2, ww_2);
  STORE_RT(3, ss_3, ww_3);
#undef STORE_RT
}

extern "C" void kernel_launch(void* const* d_in, const int* in_sizes, int n_in,
                              void* d_out, int out_size, void* d_ws, size_t ws_size,
                              hipStream_t stream) {
  const float* x         = (const float*)d_in[0];
  const float* W_embed   = (const float*)d_in[1];
  const float* b_embed   = (const float*)d_in[2];
  const float* emb_table = (const float*)d_in[3];
  const float* centroids = (const float*)d_in[4];
  const float* W2        = (const float*)d_in[5];
  const float* b2        = (const float*)d_in[6];
  float* out = (float*)d_out;

  float* pre = (float*)d_ws;                              // 512 floats
  _Float16* cent_swz = (_Float16*)((char*)d_ws + 2048);   // 256*128 f16

  precompute_kernel<<<1, NCLUST, 0, stream>>>(centroids, W2, pre);
  split_kernel<<<(NCLUST * 16) / 256, 256, 0, stream>>>(centroids, cent_swz);
  main_kernel<<<NTOK / (64 * RT), 256, 65536, stream>>>(x, W_embed, b_embed,
                                                        emb_table, b2, pre,
                                                        cent_swz, out);
}